// Round 2
// baseline (477.153 us; speedup 1.0000x reference)
//
#include <hip/hip_runtime.h>
#include <hip/hip_bf16.h>

// One-hot expansion: mask [1,1,256,256,48] fp32 labels in 0..40 ->
// out [1,40,256,256,48] fp32, out[n,v] = (mask[v] == n+1).
//
// R1 lesson: 40 interleaved store streams per wave (plane stride 12.6 MB)
// ran at 1 TB/s; one plane per blockIdx.y with contiguous float4 stores
// fixed the write side.
//
// R2/R3 theory: the onehot dispatch itself is ~155 us (the 474 us bench
// figure includes the harness's ~318 us re-poison fill). 155 us ==
// (503 MB writes + ~490 MB mask re-fetch) / 6.3 TB/s: the write stream
// cycles the 256 MB LLC every launch, evicting the 12.6 MB mask between
// plane passes, so the 40x mask re-reads miss to HBM. Fix: NON-TEMPORAL
// output stores (nt bit -> no-allocate/evict-first in L2+MALL) so the
// write stream doesn't displace the mask; mask then stays LLC-resident
// and HBM fetch drops to ~13 MB.
//
// R3 fix over R2: __builtin_nontemporal_store requires a clang
// ext_vector_type, not HIP's float4 class. Store via a native f32x4.

constexpr int V = 256 * 256 * 48;   // 3,145,728 voxels per plane
constexpr int N_LABELS = 40;

typedef float f32x4 __attribute__((ext_vector_type(4)));

__global__ __launch_bounds__(256)
void onehot_kernel(const float* __restrict__ mask, float* __restrict__ out) {
    const int i = (blockIdx.x * blockDim.x + threadIdx.x) * 4;  // voxel index
    const int n = blockIdx.y;                                   // label plane
    const float lab = (float)(n + 1);

    const f32x4 m = *reinterpret_cast<const f32x4*>(mask + i);

    f32x4 o;
    o.x = (m.x == lab) ? 1.0f : 0.0f;
    o.y = (m.y == lab) ? 1.0f : 0.0f;
    o.z = (m.z == lab) ? 1.0f : 0.0f;
    o.w = (m.w == lab) ? 1.0f : 0.0f;

    // Non-temporal: stream the write past L2/MALL without allocating, so the
    // mask (12.6 MB) survives in the LLC across all 40 plane passes.
    __builtin_nontemporal_store(o, reinterpret_cast<f32x4*>(out + (size_t)n * V + i));
}

extern "C" void kernel_launch(void* const* d_in, const int* in_sizes, int n_in,
                              void* d_out, int out_size, void* d_ws, size_t ws_size,
                              hipStream_t stream) {
    const float* mask = (const float*)d_in[0];
    float* out = (float*)d_out;

    const int threads = 256;
    const int blocks_x = (V / 4) / threads;  // 3,072 chunks per plane
    dim3 grid(blocks_x, N_LABELS);           // 122,880 blocks total

    onehot_kernel<<<grid, threads, 0, stream>>>(mask, out);
}